// Round 12
// baseline (119.688 us; speedup 1.0000x reference)
//
#include <hip/hip_runtime.h>

// PTConv fused: out[i] = (sum_{e: dst=i} relu([x_src, pos_s-pos_i] @ W1 + b1)) @ W2 + deg(i)*b2
// Pipeline: two-phase radix bucket sort (super-buckets of 1024 nodes -> 16-node fine
// buckets) -> per-bucket fused LDS counting-sort with bf16-packed features (8B/edge,
// ds_read_b64 broadcast) + packed-f32 relu-MLP aggregation -> MFMA bf16 GEMM for @W2.
// R12: BNODES 16 (3125 blocks -> occupancy no longer grid-limited), EPBA 1024.

#define HIDDEN 128
#define BNODES 16       // nodes per fine bucket
#define BSH 4           // log2(BNODES)
#define SUPSH 10        // super bucket = dst >> 10 (1024 nodes = 64 fine buckets)
#define CAPA 36864      // slots per super bucket (avg 32.7K; +23 sigma)
#define CAPF 768        // slots per fine bucket (avg 512; +11 sigma)
#define EPBA 1024       // edges per phase-A block
#define KSUB 32         // phase-B blocks per super bucket
#define CAP 1536        // edges per LDS chunk in k_main (CAP/256 = 6 per thread)
#define W2LD 136        // padded leading dim for W2^T in LDS (bf16 elems)

typedef float v2f __attribute__((ext_vector_type(2)));
typedef short bf16x8 __attribute__((ext_vector_type(8)));
typedef float f32x4 __attribute__((ext_vector_type(4)));

__device__ __forceinline__ unsigned short f2bf(float f) {
    unsigned int u = __float_as_uint(f);
    u += 0x7fffu + ((u >> 16) & 1u);   // round-to-nearest-even
    return (unsigned short)(u >> 16);
}

// Phase A: scatter edges into super buckets. entry = src<<10 | (dst & 1023).
// bcurA holds RELATIVE fill counts (memset 0).
__global__ __launch_bounds__(256) void k_scatA(const int* __restrict__ src,
                                               const int* __restrict__ dst,
                                               int* __restrict__ bcurA,
                                               unsigned int* __restrict__ pairsA,
                                               int E, int NSUP) {
    __shared__ int h[64];
    __shared__ int hb[64];
    int tid = threadIdx.x;
    if (tid < 64) h[tid] = 0;
    __syncthreads();
    int base = blockIdx.x * EPBA;
    int lim = base + EPBA; if (lim > E) lim = E;
    for (int i = base + tid; i < lim; i += 256) atomicAdd(&h[dst[i] >> SUPSH], 1);
    __syncthreads();
    if (tid < NSUP) {
        int c = h[tid];
        hb[tid] = c ? atomicAdd(&bcurA[tid], c) : 0;
        h[tid] = 0;
    }
    __syncthreads();
    for (int i = base + tid; i < lim; i += 256) {
        int d = dst[i];
        int s = d >> SUPSH;
        int loc = hb[s] + atomicAdd(&h[s], 1);
        if (loc < CAPA)    // statistical never-trip overflow guard
            pairsA[s * CAPA + loc] = ((unsigned int)src[i] << SUPSH) | (unsigned int)(d & 1023);
    }
}

// Phase B: per super bucket, KSUB blocks re-scatter its edges into 64 fine buckets
// of 16 nodes. fine entry = src<<4 | (dst & 15). bcurF relative (memset 0).
__global__ __launch_bounds__(256) void k_scatB(const int* __restrict__ bcurA,
                                               const unsigned int* __restrict__ pairsA,
                                               int* __restrict__ bcurF,
                                               unsigned int* __restrict__ pairsF,
                                               int NB) {
    __shared__ int h[64];
    __shared__ int hb[64];
    int tid = threadIdx.x;
    int s = blockIdx.x / KSUB;
    int k = blockIdx.x % KSUB;
    int base0 = s * CAPA;
    int ec = bcurA[s]; if (ec > CAPA) ec = CAPA;
    int slice = (ec + KSUB - 1) / KSUB;
    int lo = base0 + k * slice;
    int hi = lo + slice; { int e1 = base0 + ec; if (hi > e1) hi = e1; }
    if (tid < 64) h[tid] = 0;
    __syncthreads();
    for (int i = lo + tid; i < hi; i += 256) atomicAdd(&h[(pairsA[i] >> BSH) & 63u], 1);
    __syncthreads();
    if (tid < 64) {
        int c = h[tid];
        int fb = s * 64 + tid;
        hb[tid] = (c && fb < NB) ? atomicAdd(&bcurF[fb], c) : 0;
        h[tid] = 0;
    }
    __syncthreads();
    for (int i = lo + tid; i < hi; i += 256) {
        unsigned int e = pairsA[i];
        int fbl = (int)((e >> BSH) & 63u);
        int fb = s * 64 + fbl;
        int loc = hb[fbl] + atomicAdd(&h[fbl], 1);
        if (fb < NB && loc < CAPF)   // statistical never-trip overflow guard
            pairsF[(size_t)fb * CAPF + loc] = ((e >> SUPSH) << BSH) | (e & 15u);
    }
}

// One block per fine bucket of 16 nodes. Counting-sort edges by local node id in
// LDS, packing features (a, rx, ry) as 3x bf16 into 8B during the place pass;
// per-node aggregation reads one b64 broadcast per edge + packed-f32 MLP.
__global__ __launch_bounds__(256) void k_main(const float* __restrict__ x,
                                              const float* __restrict__ pos,
                                              const float* __restrict__ W1,
                                              const float* __restrict__ b1,
                                              const int* __restrict__ bcurF,
                                              const unsigned int* __restrict__ pairs,
                                              float* __restrict__ agg,
                                              int* __restrict__ deg, int N) {
    __shared__ uint2 f_s[CAP];           // 12 KiB (bf16-packed a,rx,ry)
    __shared__ int cnt[BNODES];
    __shared__ int offn[BNODES + 1];
    __shared__ int cur[BNODES];

    int tid = threadIdx.x, lane = tid & 63, w = tid >> 6;
    int b = blockIdx.x;
    int n0 = b * BNODES;
    int e0 = b * CAPF;
    int ec = bcurF[b]; if (ec > CAPF) ec = CAPF;
    int e1 = e0 + ec;

    int c0 = 2 * lane;
    v2f w10 = { W1[c0],              W1[c0 + 1] };
    v2f w11 = { W1[HIDDEN + c0],     W1[HIDDEN + c0 + 1] };
    v2f w12 = { W1[2 * HIDDEN + c0], W1[2 * HIDDEN + c0 + 1] };
    v2f b1v = { b1[c0], b1[c0 + 1] };
    const v2f zero = { 0.f, 0.f };
    const float2* pos2 = (const float2*)pos;

    v2f acc[4];
    int dga[4];
    #pragma unroll
    for (int s = 0; s < 4; ++s) { acc[s] = zero; dga[s] = 0; }

    for (int cbeg = e0; cbeg < e1; cbeg += CAP) {
        int ccnt = e1 - cbeg; if (ccnt > CAP) ccnt = CAP;
        if (tid < BNODES) cnt[tid] = 0;
        __syncthreads();
        // register-cache this thread's chunk entries (static unroll, no scratch)
        unsigned int rr0 = 0, rr1 = 0, rr2 = 0, rr3 = 0, rr4 = 0, rr5 = 0;
        if (tid + 0 * 256 < ccnt) rr0 = pairs[cbeg + tid + 0 * 256];
        if (tid + 1 * 256 < ccnt) rr1 = pairs[cbeg + tid + 1 * 256];
        if (tid + 2 * 256 < ccnt) rr2 = pairs[cbeg + tid + 2 * 256];
        if (tid + 3 * 256 < ccnt) rr3 = pairs[cbeg + tid + 3 * 256];
        if (tid + 4 * 256 < ccnt) rr4 = pairs[cbeg + tid + 4 * 256];
        if (tid + 5 * 256 < ccnt) rr5 = pairs[cbeg + tid + 5 * 256];
        // count pass
        if (tid + 0 * 256 < ccnt) atomicAdd(&cnt[rr0 & 15u], 1);
        if (tid + 1 * 256 < ccnt) atomicAdd(&cnt[rr1 & 15u], 1);
        if (tid + 2 * 256 < ccnt) atomicAdd(&cnt[rr2 & 15u], 1);
        if (tid + 3 * 256 < ccnt) atomicAdd(&cnt[rr3 & 15u], 1);
        if (tid + 4 * 256 < ccnt) atomicAdd(&cnt[rr4 & 15u], 1);
        if (tid + 5 * 256 < ccnt) atomicAdd(&cnt[rr5 & 15u], 1);
        __syncthreads();
        if (tid < BNODES) {
            int v = cnt[tid];
            int sc = v;
            #pragma unroll
            for (int d = 1; d < BNODES; d <<= 1) {
                int u = __shfl_up(sc, d);
                if (lane >= d) sc += u;
            }
            offn[tid + 1] = sc;
            if (tid == 0) offn[0] = 0;
            cur[tid] = sc - v;  // exclusive
        }
        __syncthreads();
        // place pass: gather + compute features, pack bf16, one b64 write per edge
        #pragma unroll
        for (int q = 0; q < 6; ++q) {
            unsigned int r = q == 0 ? rr0 : q == 1 ? rr1 : q == 2 ? rr2
                           : q == 3 ? rr3 : q == 4 ? rr4 : rr5;
            if (tid + q * 256 < ccnt) {
                int j = (int)(r >> BSH);
                int local = (int)(r & 15u);
                float a = x[j];
                float2 pj = pos2[j];
                float2 pi = pos2[n0 + local];
                unsigned int lo = ((unsigned int)f2bf(pj.x - pi.x) << 16) | f2bf(a);
                unsigned int hi = f2bf(pj.y - pi.y);
                int p = atomicAdd(&cur[local], 1);
                f_s[p] = make_uint2(lo, hi);
            }
        }
        __syncthreads();
        // compute pass: one b64 broadcast per edge, unpack bf16, packed-f32 MLP
        #pragma unroll
        for (int s = 0; s < 4; ++s) {
            int l = w * 4 + s;
            int sb = offn[l], se = offn[l + 1];
            dga[s] += se - sb;
            v2f A = acc[s];
            #pragma unroll 4
            for (int t = sb; t < se; ++t) {
                uint2 r = f_s[t];
                float a  = __uint_as_float(r.x << 16);
                float rx = __uint_as_float(r.x & 0xffff0000u);
                float ry = __uint_as_float(r.y << 16);
                v2f h = a * w10 + b1v;
                h = rx * w11 + h;
                h = ry * w12 + h;
                h = __builtin_elementwise_max(h, zero);
                A += h;
            }
            acc[s] = A;
        }
        __syncthreads();
    }

    #pragma unroll
    for (int s = 0; s < 4; ++s) {
        int l = w * 4 + s;
        int node = n0 + l;
        if (node < N) {
            ((v2f*)&agg[(size_t)node * HIDDEN])[lane] = acc[s];
            if (lane == 0) deg[node] = dga[s];
        }
    }
}

// MFMA GEMM: out = agg @ W2 + deg*b2, in place on d_out (agg==out, f32).
// Each block: 64 rows (4 waves x 16). W2^T staged bf16 in LDS (pad 136).
__global__ __launch_bounds__(256) void k_w2(float* __restrict__ agg,
                                            const float* __restrict__ W2,
                                            const float* __restrict__ b2,
                                            const int* __restrict__ deg, int N) {
    __shared__ unsigned short w2t[HIDDEN * W2LD];  // 34 KiB, W2^T[c][k]
    int tid = threadIdx.x;
    for (int idx = tid; idx < HIDDEN * HIDDEN; idx += 256) {
        int k = idx >> 7, c = idx & 127;            // idx = k*128 + c
        w2t[c * W2LD + k] = f2bf(W2[idx]);
    }
    __syncthreads();

    int lane = tid & 63, w = tid >> 6;
    int row0 = blockIdx.x * 64 + w * 16;
    if (row0 >= N) return;

    int rA = row0 + (lane & 15);
    int koff = (lane >> 4) * 8;
    bool okA = rA < N;

    bf16x8 a[4];
    #pragma unroll
    for (int k0 = 0; k0 < 4; ++k0) {
        float4 fa = {0.f,0.f,0.f,0.f}, fb = {0.f,0.f,0.f,0.f};
        if (okA) {
            const float4* p = (const float4*)&agg[(size_t)rA * HIDDEN + k0 * 32 + koff];
            fa = p[0]; fb = p[1];
        }
        bf16x8 v;
        v[0] = (short)f2bf(fa.x); v[1] = (short)f2bf(fa.y);
        v[2] = (short)f2bf(fa.z); v[3] = (short)f2bf(fa.w);
        v[4] = (short)f2bf(fb.x); v[5] = (short)f2bf(fb.y);
        v[6] = (short)f2bf(fb.z); v[7] = (short)f2bf(fb.w);
        a[k0] = v;
    }

    f32x4 acc[8];
    #pragma unroll
    for (int ct = 0; ct < 8; ++ct) acc[ct] = (f32x4){0.f,0.f,0.f,0.f};

    #pragma unroll
    for (int ct = 0; ct < 8; ++ct) {
        int col = ct * 16 + (lane & 15);
        #pragma unroll
        for (int k0 = 0; k0 < 4; ++k0) {
            bf16x8 bfrag = *(const bf16x8*)&w2t[col * W2LD + k0 * 32 + koff];
            acc[ct] = __builtin_amdgcn_mfma_f32_16x16x32_bf16(a[k0], bfrag, acc[ct], 0, 0, 0);
        }
    }

    int mbase = row0 + (lane >> 4) * 4;
    float dg[4];
    #pragma unroll
    for (int i = 0; i < 4; ++i) dg[i] = (mbase + i < N) ? (float)deg[mbase + i] : 0.f;

    #pragma unroll
    for (int ct = 0; ct < 8; ++ct) {
        int col = ct * 16 + (lane & 15);
        float b2c = b2[col];
        #pragma unroll
        for (int i = 0; i < 4; ++i) {
            int r = mbase + i;
            if (r < N) agg[(size_t)r * HIDDEN + col] = acc[ct][i] + dg[i] * b2c;
        }
    }
}

extern "C" void kernel_launch(void* const* d_in, const int* in_sizes, int n_in,
                              void* d_out, int out_size, void* d_ws, size_t ws_size,
                              hipStream_t stream) {
    const float* x   = (const float*)d_in[0];
    const float* pos = (const float*)d_in[1];
    const float* W1  = (const float*)d_in[2];
    const float* b1  = (const float*)d_in[3];
    const float* W2  = (const float*)d_in[4];
    const float* b2  = (const float*)d_in[5];
    const int*   ei  = (const int*)d_in[6];

    int N = in_sizes[0];        // x is [N,1]
    int E = in_sizes[6] / 2;    // edge_index is [2,E]
    const int* src = ei;
    const int* dst = ei + E;
    float* out = (float*)d_out;

    int NB   = (N + BNODES - 1) / BNODES;          // fine buckets (16 nodes)
    int NSUP = (N + 1023) >> SUPSH;                // super buckets

    // workspace: bcurA[64] | bcurF[NB] | deg[N] | pairsA[NSUP*CAPA] | pairsF[NB*CAPF]
    int* bcurA = (int*)d_ws;
    int* bcurF = bcurA + 64;
    int* deg   = bcurF + NB;
    unsigned int* pairsA = (unsigned int*)(deg + N);
    unsigned int* pairsF = pairsA + (size_t)NSUP * CAPA;

    int gribsA = (E + EPBA - 1) / EPBA;

    hipMemsetAsync(bcurA, 0, (64 + (size_t)NB) * sizeof(int), stream);
    k_scatA<<<gribsA, 256, 0, stream>>>(src, dst, bcurA, pairsA, E, NSUP);
    k_scatB<<<NSUP * KSUB, 256, 0, stream>>>(bcurA, pairsA, bcurF, pairsF, NB);
    k_main<<<NB, 256, 0, stream>>>(x, pos, W1, b1, bcurF, pairsF, out, deg, N);
    k_w2<<<(N + 63) / 64, 256, 0, stream>>>(out, W2, b2, deg, N);
}

// Round 13
// 99.713 us; speedup vs baseline: 1.2003x; 1.2003x over previous
//
#include <hip/hip_runtime.h>

// PTConv fused: out[i] = (sum_{e: dst=i} relu([x_src, pos_s-pos_i] @ W1 + b1)) @ W2 + deg(i)*b2
// Pipeline: two-phase radix bucket sort (49 super-buckets of 1024 nodes -> 16-node fine
// buckets), both phases 512-thread + int4-vectorized loads; per-bucket fused LDS
// counting-sort (single 768-slot chunk) with cvt_pk-packed features (8B/edge: bf16 rx,ry
// + f32 a); per-node packed-f32 relu-MLP aggregation; MFMA bf16 GEMM for @W2.

#define HIDDEN 128
#define BNODES 16       // nodes per fine bucket
#define BSH 4           // log2(BNODES)
#define SUPSH 10        // super bucket = dst >> 10 (1024 nodes = 64 fine buckets)
#define CAPA 36864      // slots per super bucket (avg 32.7K; +23 sigma)
#define CAPF 768        // slots per fine bucket (avg 512; +11 sigma)
#define EPBA 2048       // edges per phase-A block
#define SThrA 512
#define KSUB 16         // phase-B blocks per super bucket
#define SThrB 512
#define W2LD 136        // padded leading dim for W2^T in LDS (bf16 elems)

typedef float v2f __attribute__((ext_vector_type(2)));
typedef short bf16x8 __attribute__((ext_vector_type(8)));
typedef float f32x4 __attribute__((ext_vector_type(4)));

__device__ __forceinline__ unsigned cvt_pk_bf16(float lo, float hi) {
    unsigned r;
    asm("v_cvt_pk_bf16_f32 %0, %1, %2" : "=v"(r) : "v"(lo), "v"(hi));
    return r;   // [15:0]=bf16(lo), [31:16]=bf16(hi)
}

__device__ __forceinline__ unsigned short f2bf(float f) {
    unsigned int u = __float_as_uint(f);
    u += 0x7fffu + ((u >> 16) & 1u);   // round-to-nearest-even
    return (unsigned short)(u >> 16);
}

// Phase A: scatter edges into super buckets. entry = src<<10 | (dst & 1023).
// bcurA holds RELATIVE fill counts (memset 0). 512 thr, int4 loads.
__global__ __launch_bounds__(SThrA) void k_scatA(const int* __restrict__ src,
                                                 const int* __restrict__ dst,
                                                 int* __restrict__ bcurA,
                                                 unsigned int* __restrict__ pairsA,
                                                 int E, int NSUP) {
    __shared__ int h[64];
    __shared__ int hb[64];
    int tid = threadIdx.x;
    if (tid < 64) h[tid] = 0;
    __syncthreads();
    int base = blockIdx.x * EPBA;
    int lim = base + EPBA; if (lim > E) lim = E;
    int n = lim - base;
    int n4 = ((E & 3) == 0) ? (n >> 2) : 0;    // vector path only if aligned
    const int4* d4 = (const int4*)(dst + base);
    const int4* s4 = (const int4*)(src + base);
    for (int i = tid; i < n4; i += SThrA) {
        int4 d = d4[i];
        atomicAdd(&h[d.x >> SUPSH], 1);
        atomicAdd(&h[d.y >> SUPSH], 1);
        atomicAdd(&h[d.z >> SUPSH], 1);
        atomicAdd(&h[d.w >> SUPSH], 1);
    }
    for (int i = base + (n4 << 2) + tid; i < lim; i += SThrA)
        atomicAdd(&h[dst[i] >> SUPSH], 1);
    __syncthreads();
    if (tid < 64) {
        int c = h[tid];
        hb[tid] = (c && tid < NSUP) ? atomicAdd(&bcurA[tid], c) : 0;
        h[tid] = 0;
    }
    __syncthreads();
#define PUTA(dd, ss) { int sb = (dd) >> SUPSH; int loc = hb[sb] + atomicAdd(&h[sb], 1); \
        if (loc < CAPA) pairsA[sb * CAPA + loc] = ((unsigned)(ss) << SUPSH) | (unsigned)((dd) & 1023); }
    for (int i = tid; i < n4; i += SThrA) {
        int4 d = d4[i];
        int4 s = s4[i];
        PUTA(d.x, s.x) PUTA(d.y, s.y) PUTA(d.z, s.z) PUTA(d.w, s.w)
    }
    for (int i = base + (n4 << 2) + tid; i < lim; i += SThrA) {
        int dd = dst[i], ss = src[i];
        PUTA(dd, ss)
    }
#undef PUTA
}

// Phase B: per super bucket, KSUB blocks re-scatter its edges into 64 fine buckets
// of 16 nodes. fine entry = src<<4 | (dst & 15). bcurF relative (memset 0).
__global__ __launch_bounds__(SThrB) void k_scatB(const int* __restrict__ bcurA,
                                                 const unsigned int* __restrict__ pairsA,
                                                 int* __restrict__ bcurF,
                                                 unsigned int* __restrict__ pairsF,
                                                 int NB) {
    __shared__ int h[64];
    __shared__ int hb[64];
    int tid = threadIdx.x;
    int s = blockIdx.x / KSUB;
    int k = blockIdx.x % KSUB;
    int base0 = s * CAPA;
    int ec = bcurA[s]; if (ec > CAPA) ec = CAPA;
    int slice = (((ec + KSUB - 1) / KSUB) + 3) & ~3;   // 4-aligned
    int lo = base0 + k * slice;
    int e1 = base0 + ec;
    int hi = lo + slice; if (hi > e1) hi = e1;
    int n = hi - lo; if (n < 0) n = 0;
    int n4 = n >> 2;                                    // lo is 4-aligned
    const uint4* p4 = (const uint4*)(pairsA + lo);
    if (tid < 64) h[tid] = 0;
    __syncthreads();
    for (int i = tid; i < n4; i += SThrB) {
        uint4 e = p4[i];
        atomicAdd(&h[(e.x >> BSH) & 63u], 1);
        atomicAdd(&h[(e.y >> BSH) & 63u], 1);
        atomicAdd(&h[(e.z >> BSH) & 63u], 1);
        atomicAdd(&h[(e.w >> BSH) & 63u], 1);
    }
    for (int i = lo + (n4 << 2) + tid; i < hi; i += SThrB)
        atomicAdd(&h[(pairsA[i] >> BSH) & 63u], 1);
    __syncthreads();
    if (tid < 64) {
        int c = h[tid];
        int fb = s * 64 + tid;
        hb[tid] = (c && fb < NB) ? atomicAdd(&bcurF[fb], c) : 0;
        h[tid] = 0;
    }
    __syncthreads();
#define PUTB(ee) { int fbl = (int)(((ee) >> BSH) & 63u); int fb = s * 64 + fbl; \
        int loc = hb[fbl] + atomicAdd(&h[fbl], 1); \
        if (fb < NB && loc < CAPF) pairsF[(size_t)fb * CAPF + loc] = (((ee) >> SUPSH) << BSH) | ((ee) & 15u); }
    for (int i = tid; i < n4; i += SThrB) {
        uint4 e = p4[i];
        PUTB(e.x) PUTB(e.y) PUTB(e.z) PUTB(e.w)
    }
    for (int i = lo + (n4 << 2) + tid; i < hi; i += SThrB) {
        unsigned int e = pairsA[i];
        PUTB(e)
    }
#undef PUTB
}

// One block per fine bucket of 16 nodes, single 768-edge chunk. Counting-sort by
// local node id in LDS; place pass packs (rx,ry) via v_cvt_pk_bf16_f32 + raw f32 a
// into 8B; compute pass: one b64 broadcast per edge, 2-instr unpack, packed-f32 MLP.
__global__ __launch_bounds__(256) void k_main(const float* __restrict__ x,
                                              const float* __restrict__ pos,
                                              const float* __restrict__ W1,
                                              const float* __restrict__ b1,
                                              const int* __restrict__ bcurF,
                                              const unsigned int* __restrict__ pairs,
                                              float* __restrict__ agg,
                                              int* __restrict__ deg, int N) {
    __shared__ uint2 f_s[CAPF];          // 6 KiB
    __shared__ int cnt[BNODES];
    __shared__ int offn[BNODES + 1];
    __shared__ int cur[BNODES];

    int tid = threadIdx.x, lane = tid & 63, w = tid >> 6;
    int b = blockIdx.x;
    int n0 = b * BNODES;
    int e0 = b * CAPF;
    int ec = bcurF[b]; if (ec > CAPF) ec = CAPF;

    int c0 = 2 * lane;
    v2f w10 = { W1[c0],              W1[c0 + 1] };
    v2f w11 = { W1[HIDDEN + c0],     W1[HIDDEN + c0 + 1] };
    v2f w12 = { W1[2 * HIDDEN + c0], W1[2 * HIDDEN + c0 + 1] };
    v2f b1v = { b1[c0], b1[c0 + 1] };
    const v2f zero = { 0.f, 0.f };
    const float2* pos2 = (const float2*)pos;

    if (tid < BNODES) cnt[tid] = 0;
    __syncthreads();
    // register-cache entries (768/256 = 3 per thread) + count pass
    unsigned int rr0 = 0, rr1 = 0, rr2 = 0;
    if (tid + 0 * 256 < ec) rr0 = pairs[e0 + tid + 0 * 256];
    if (tid + 1 * 256 < ec) rr1 = pairs[e0 + tid + 1 * 256];
    if (tid + 2 * 256 < ec) rr2 = pairs[e0 + tid + 2 * 256];
    if (tid + 0 * 256 < ec) atomicAdd(&cnt[rr0 & 15u], 1);
    if (tid + 1 * 256 < ec) atomicAdd(&cnt[rr1 & 15u], 1);
    if (tid + 2 * 256 < ec) atomicAdd(&cnt[rr2 & 15u], 1);
    __syncthreads();
    if (tid < BNODES) {
        int v = cnt[tid];
        int sc = v;
        #pragma unroll
        for (int d = 1; d < BNODES; d <<= 1) {
            int u = __shfl_up(sc, d);
            if (lane >= d) sc += u;
        }
        offn[tid + 1] = sc;
        if (tid == 0) offn[0] = 0;
        cur[tid] = sc - v;  // exclusive
    }
    __syncthreads();
    // place pass: gather, compute (a, rx, ry), cvt_pk pack, one b64 write per edge
    #pragma unroll
    for (int q = 0; q < 3; ++q) {
        unsigned int r = q == 0 ? rr0 : q == 1 ? rr1 : rr2;
        if (tid + q * 256 < ec) {
            int j = (int)(r >> BSH);
            int local = (int)(r & 15u);
            float a = x[j];
            float2 pj = pos2[j];
            float2 pi = pos2[n0 + local];
            unsigned pk = cvt_pk_bf16(pj.x - pi.x, pj.y - pi.y);
            int p = atomicAdd(&cur[local], 1);
            f_s[p] = make_uint2(pk, __float_as_uint(a));
        }
    }
    __syncthreads();
    // compute pass: one b64 broadcast per edge, 2-instr unpack, packed-f32 MLP
    v2f acc[4];
    int dga[4];
    #pragma unroll
    for (int s = 0; s < 4; ++s) {
        int l = w * 4 + s;
        int sb = offn[l], se = offn[l + 1];
        dga[s] = se - sb;
        v2f A = zero;
        #pragma unroll 4
        for (int t = sb; t < se; ++t) {
            uint2 r = f_s[t];
            float rx = __uint_as_float(r.x << 16);
            float ry = __uint_as_float(r.x & 0xffff0000u);
            float a  = __uint_as_float(r.y);
            v2f h = a * w10 + b1v;
            h = rx * w11 + h;
            h = ry * w12 + h;
            h = __builtin_elementwise_max(h, zero);
            A += h;
        }
        acc[s] = A;
    }

    #pragma unroll
    for (int s = 0; s < 4; ++s) {
        int l = w * 4 + s;
        int node = n0 + l;
        if (node < N) {
            ((v2f*)&agg[(size_t)node * HIDDEN])[lane] = acc[s];
            if (lane == 0) deg[node] = dga[s];
        }
    }
}

// MFMA GEMM: out = agg @ W2 + deg*b2, in place on d_out (agg==out, f32).
// Each block: 64 rows (4 waves x 16). W2^T staged bf16 in LDS (pad 136).
__global__ __launch_bounds__(256) void k_w2(float* __restrict__ agg,
                                            const float* __restrict__ W2,
                                            const float* __restrict__ b2,
                                            const int* __restrict__ deg, int N) {
    __shared__ unsigned short w2t[HIDDEN * W2LD];  // 34 KiB, W2^T[c][k]
    int tid = threadIdx.x;
    for (int idx = tid; idx < HIDDEN * HIDDEN; idx += 256) {
        int k = idx >> 7, c = idx & 127;            // idx = k*128 + c
        w2t[c * W2LD + k] = f2bf(W2[idx]);
    }
    __syncthreads();

    int lane = tid & 63, w = tid >> 6;
    int row0 = blockIdx.x * 64 + w * 16;
    if (row0 >= N) return;

    int rA = row0 + (lane & 15);
    int koff = (lane >> 4) * 8;
    bool okA = rA < N;

    bf16x8 a[4];
    #pragma unroll
    for (int k0 = 0; k0 < 4; ++k0) {
        float4 fa = {0.f,0.f,0.f,0.f}, fb = {0.f,0.f,0.f,0.f};
        if (okA) {
            const float4* p = (const float4*)&agg[(size_t)rA * HIDDEN + k0 * 32 + koff];
            fa = p[0]; fb = p[1];
        }
        union { uint4 u; bf16x8 v; } cv;
        cv.u.x = cvt_pk_bf16(fa.x, fa.y);
        cv.u.y = cvt_pk_bf16(fa.z, fa.w);
        cv.u.z = cvt_pk_bf16(fb.x, fb.y);
        cv.u.w = cvt_pk_bf16(fb.z, fb.w);
        a[k0] = cv.v;
    }

    f32x4 acc[8];
    #pragma unroll
    for (int ct = 0; ct < 8; ++ct) acc[ct] = (f32x4){0.f,0.f,0.f,0.f};

    #pragma unroll
    for (int ct = 0; ct < 8; ++ct) {
        int col = ct * 16 + (lane & 15);
        #pragma unroll
        for (int k0 = 0; k0 < 4; ++k0) {
            bf16x8 bfrag = *(const bf16x8*)&w2t[col * W2LD + k0 * 32 + koff];
            acc[ct] = __builtin_amdgcn_mfma_f32_16x16x32_bf16(a[k0], bfrag, acc[ct], 0, 0, 0);
        }
    }

    int mbase = row0 + (lane >> 4) * 4;
    float dg[4];
    #pragma unroll
    for (int i = 0; i < 4; ++i) dg[i] = (mbase + i < N) ? (float)deg[mbase + i] : 0.f;

    #pragma unroll
    for (int ct = 0; ct < 8; ++ct) {
        int col = ct * 16 + (lane & 15);
        float b2c = b2[col];
        #pragma unroll
        for (int i = 0; i < 4; ++i) {
            int r = mbase + i;
            if (r < N) agg[(size_t)r * HIDDEN + col] = acc[ct][i] + dg[i] * b2c;
        }
    }
}

extern "C" void kernel_launch(void* const* d_in, const int* in_sizes, int n_in,
                              void* d_out, int out_size, void* d_ws, size_t ws_size,
                              hipStream_t stream) {
    const float* x   = (const float*)d_in[0];
    const float* pos = (const float*)d_in[1];
    const float* W1  = (const float*)d_in[2];
    const float* b1  = (const float*)d_in[3];
    const float* W2  = (const float*)d_in[4];
    const float* b2  = (const float*)d_in[5];
    const int*   ei  = (const int*)d_in[6];

    int N = in_sizes[0];        // x is [N,1]
    int E = in_sizes[6] / 2;    // edge_index is [2,E]
    const int* src = ei;
    const int* dst = ei + E;
    float* out = (float*)d_out;

    int NB   = (N + BNODES - 1) / BNODES;          // fine buckets (16 nodes)
    int NSUP = (N + 1023) >> SUPSH;                // super buckets

    // workspace: bcurA[64] | bcurF[NB] | deg[N] | pairsA[NSUP*CAPA] | pairsF[NB*CAPF]
    int* bcurA = (int*)d_ws;
    int* bcurF = bcurA + 64;
    int* deg   = bcurF + NB;
    unsigned int* pairsA = (unsigned int*)(deg + N);
    unsigned int* pairsF = pairsA + (size_t)NSUP * CAPA;

    int gribsA = (E + EPBA - 1) / EPBA;

    hipMemsetAsync(bcurA, 0, (64 + (size_t)NB) * sizeof(int), stream);
    k_scatA<<<gribsA, SThrA, 0, stream>>>(src, dst, bcurA, pairsA, E, NSUP);
    k_scatB<<<NSUP * KSUB, SThrB, 0, stream>>>(bcurA, pairsA, bcurF, pairsF, NB);
    k_main<<<NB, 256, 0, stream>>>(x, pos, W1, b1, bcurF, pairsF, out, deg, N);
    k_w2<<<(N + 63) / 64, 256, 0, stream>>>(out, W2, b2, deg, N);
}